// Round 4
// baseline (274.822 us; speedup 1.0000x reference)
//
#include <hip/hip_runtime.h>
#include <math.h>

// Problem constants (N,T,V,M,n = 32,64,25,2,16)
#define NS     32        // batch samples
#define BBATCH 3200      // matrices per sample (T*V*M)
#define NMAT   102400    // total matrices
#define ST     20        // LDS row stride: rows 16B-aligned, col reads ~2-way banks (free)
#define IX(i,j) ((i)*ST+(j))
#define MSZ    (16*ST)
#define SLAB   324       // per-matrix slab (16*20 + 4 pad), 16B-aligned

// workspace layout (float offsets)
#define PART_O 0         // 512*256 partial sums
#define XM_O   131072    // 32*256 per-sample means
#define WI_O   139264    // invsqrtm(mean)  (16*16)
// end: 139520 floats = 558 KB

// Polynomial degrees (spectra concentrate near I after trace scaling; truncation ~1e-10)
#define NS_IT  5
#define LOG_M  8
#define EXP_M  8

// ---------------- wave-local 16x16 helpers ----------------
// All 64 lanes of ONE wave execute; lane l owns row i=l>>2, cols j0..j0+3.
// No __syncthreads: wave lockstep + s_waitcnt lgkmcnt(0) orders LDS ops.

__device__ __forceinline__ void wsync() {
  asm volatile("s_waitcnt lgkmcnt(0)" ::: "memory");
}

__device__ __forceinline__ void g2l_w(const float* __restrict__ g, float* L, int l) {
  int i = l >> 2, j0 = (l & 3) << 2;
  *(float4*)&L[IX(i, j0)] = *(const float4*)&g[i * 16 + j0];
  wsync();
}

__device__ __forceinline__ void l2g_w(const float* L, float* __restrict__ g, int l) {
  int i = l >> 2, j0 = (l & 3) << 2;
  *(float4*)&g[i * 16 + j0] = *(const float4*)&L[IX(i, j0)];
}

__device__ __forceinline__ void cpy_w(const float* S, float* D, int l) {
  int i = l >> 2, j0 = (l & 3) << 2;
  float4 v = *(const float4*)&S[IX(i, j0)];
  wsync();
  *(float4*)&D[IX(i, j0)] = v;
  wsync();
}

// C = A*B (C distinct from A,B)
__device__ __forceinline__ void mm_w(const float* A, const float* B, float* C, int l) {
  int i = l >> 2, j0 = (l & 3) << 2;
  float4 acc = make_float4(0.f, 0.f, 0.f, 0.f);
  #pragma unroll
  for (int k = 0; k < 16; ++k) {
    float a = A[IX(i, k)];
    float4 b = *(const float4*)&B[IX(k, j0)];
    acc.x += a * b.x; acc.y += a * b.y; acc.z += a * b.z; acc.w += a * b.w;
  }
  wsync();
  *(float4*)&C[IX(i, j0)] = acc;
  wsync();
}

// C = s*C + d*I
__device__ __forceinline__ void mad_diag_w(float* C, float s, float d, int l) {
  int i = l >> 2, j0 = (l & 3) << 2;
  float4 p = *(float4*)&C[IX(i, j0)];
  p.x *= s; p.y *= s; p.z *= s; p.w *= s;
  if (i == j0) p.x += d; else if (i == j0 + 1) p.y += d;
  else if (i == j0 + 2) p.z += d; else if (i == j0 + 3) p.w += d;
  wsync();
  *(float4*)&C[IX(i, j0)] = p;
  wsync();
}

// C = d*I
__device__ __forceinline__ void setI_w(float* C, float d, int l) {
  int i = l >> 2, j0 = (l & 3) << 2;
  float4 p = make_float4(0.f, 0.f, 0.f, 0.f);
  if (i == j0) p.x = d; else if (i == j0 + 1) p.y = d;
  else if (i == j0 + 2) p.z = d; else if (i == j0 + 3) p.w = d;
  *(float4*)&C[IX(i, j0)] = p;
  wsync();
}

// D += S
__device__ __forceinline__ void add_w(float* D, const float* S, int l) {
  int i = l >> 2, j0 = (l & 3) << 2;
  float4 d = *(float4*)&D[IX(i, j0)];
  float4 s = *(const float4*)&S[IX(i, j0)];
  d.x += s.x; d.y += s.y; d.z += s.z; d.w += s.w;
  wsync();
  *(float4*)&D[IX(i, j0)] = d;
  wsync();
}

__device__ __forceinline__ void sym_w(float* A, int l) {
  int i = l >> 2, j0 = (l & 3) << 2;
  float4 a = *(float4*)&A[IX(i, j0)];
  float4 v;
  v.x = 0.5f * (a.x + A[IX(j0,     i)]);
  v.y = 0.5f * (a.y + A[IX(j0 + 1, i)]);
  v.z = 0.5f * (a.z + A[IX(j0 + 2, i)]);
  v.w = 0.5f * (a.w + A[IX(j0 + 3, i)]);
  wsync();
  *(float4*)&A[IX(i, j0)] = v;
  wsync();
}

__device__ __forceinline__ float trace16_w(const float* A) {
  float tr = 0.f;
  #pragma unroll
  for (int k = 0; k < 16; ++k) tr += A[IX(k, k)];
  return tr;
}

// Coupled Newton-Schulz sqrt/invsqrt. A preserved. 5 scratch buffers.
__device__ void ns_sqrtm_w(const float* A, float* Y0, float* Y1, float* Z0, float* Z1,
                           float* P, int l, float** pS, float** pZ) {
  float c = trace16_w(A) * (1.f / 16.f);
  float ic = 1.f / c;
  {
    int i = l >> 2, j0 = (l & 3) << 2;
    float4 a = *(const float4*)&A[IX(i, j0)];
    a.x *= ic; a.y *= ic; a.z *= ic; a.w *= ic;
    *(float4*)&Y0[IX(i, j0)] = a;
  }
  setI_w(Z0, 1.f, l);
  float *Y = Y0, *Yn = Y1, *Z = Z0, *Zn = Z1;
  for (int it = 0; it < NS_IT; ++it) {
    mm_w(Z, Y, P, l);                  // P = Z*Y
    mad_diag_w(P, -0.5f, 1.5f, l);     // T = (3I - P)/2
    mm_w(Y, P, Yn, l);                 // Y <- Y*T
    mm_w(P, Z, Zn, l);                 // Z <- T*Z
    float* tp = Y; Y = Yn; Yn = tp;
    tp = Z; Z = Zn; Zn = tp;
  }
  mad_diag_w(Y, sqrtf(c), 0.f, l);
  mad_diag_w(Z, 1.f / sqrtf(c), 0.f, l);
  *pS = Y; *pZ = Z;
}

// L = log(S), S ~ I+E. S destroyed. S,L,R0,R1 distinct.
__device__ void logm_w(float* S, float* L, float* R0, float* R1, int l) {
  mad_diag_w(S, 1.f, -1.f, l);         // E = S - I
  float am = ((LOG_M & 1) ? 1.f : -1.f) / (float)LOG_M;
  setI_w(R0, am, l);
  float *R = R0, *Rn = R1;
  for (int j = LOG_M - 1; j >= 1; --j) {
    mm_w(S, R, Rn, l);
    float aj = ((j & 1) ? 1.f : -1.f) / (float)j;
    mad_diag_w(Rn, 1.f, aj, l);
    float* tp = R; R = Rn; Rn = tp;
  }
  mm_w(S, R, L, l);
}

// exp(K) Horner. K preserved. Result pointer returned (R0 or R1).
__device__ float* expm_w(const float* K, float* R0, float* R1, int l) {
  setI_w(R0, 1.f, l);
  float *R = R0, *Rn = R1;
  for (int j = EXP_M; j >= 1; --j) {
    mm_w(K, R, Rn, l);
    mad_diag_w(Rn, 1.f / (float)j, 1.f, l);
    float* tp = R; R = Rn; Rn = tp;
  }
  return R;
}

// ---------------- kernels ----------------

// Partial sums: 512 blocks = 32 samples x 16 chunks of 200 matrices.
__global__ __launch_bounds__(256) void k_part(const float* __restrict__ X, float* __restrict__ ws) {
  int b = blockIdx.x >> 4;
  int c = blockIdx.x & 15;
  int t = threadIdx.x;
  int e4 = t & 63;
  int r  = t >> 6;
  const float4* X4 = (const float4*)X;
  float4 s = make_float4(0.f, 0.f, 0.f, 0.f);
  long mbase = (long)b * BBATCH + c * 200;
  for (int i = r; i < 200; i += 4) {
    float4 v = X4[(mbase + i) * 64 + e4];
    s.x += v.x; s.y += v.y; s.z += v.z; s.w += v.w;
  }
  __shared__ float4 red[256];
  red[t] = s;
  __syncthreads();
  if (t < 64) {
    float4 a = red[t], b1 = red[t + 64], c1 = red[t + 128], d = red[t + 192];
    float4 o;
    o.x = a.x + b1.x + c1.x + d.x;
    o.y = a.y + b1.y + c1.y + d.y;
    o.z = a.z + b1.z + c1.z + d.z;
    o.w = a.w + b1.w + c1.w + d.w;
    ((float4*)(ws + PART_O))[(long)blockIdx.x * 64 + t] = o;
  }
}

// ONE kernel for the whole spectral chain. 1 block x 256 threads (4 waves).
// Stage A: fold partials -> Xm. Stage B: wave0 NS(G), wave1 NS(rm).
// Stage C: 4 waves x 8 logmaps, per-wave L-accumulators (L never leaves LDS).
// Stage D: wave0: Lbar -> expm -> mean -> invsqrt -> W; geodesic -> out tail.
__global__ __launch_bounds__(256) void k_spectral(const float* __restrict__ rm,
                                                  float* __restrict__ ws,
                                                  float* __restrict__ out) {
  __shared__ __align__(16) float shA[5 * MSZ];     // Gi, Gs, Ri, Rs, (spare)
  __shared__ __align__(16) float wb[4][6 * MSZ];   // per-wave scratch
  int t = threadIdx.x, w = t >> 6, l = t & 63;
  float* Gi = &shA[0];
  float* Gs = &shA[MSZ];
  float* Ri = &shA[2 * MSZ];
  float* Rs = &shA[3 * MSZ];

  // --- stage A: fold partial sums -> per-sample means ---
  for (int o = t; o < NS * 256; o += 256) {
    int b = o >> 8, e = o & 255;
    float a = 0.f;
    for (int c = 0; c < 16; ++c) a += ws[PART_O + (b * 16 + c) * 256 + e];
    ws[XM_O + o] = a * (1.f / BBATCH);
  }
  __threadfence_block();
  __syncthreads();

  // --- stage B: wave0: G = mean(Xm) -> Gs,Gi ; wave1: rm -> Rs,Ri ---
  if (w == 0) {
    float* B = wb[0];
    int i = l >> 2, j0 = (l & 3) << 2;
    float4 a = make_float4(0.f, 0.f, 0.f, 0.f);
    for (int b = 0; b < NS; ++b) {
      float4 v = *(const float4*)&ws[XM_O + b * 256 + i * 16 + j0];
      a.x += v.x; a.y += v.y; a.z += v.z; a.w += v.w;
    }
    float s = 1.f / NS;
    a.x *= s; a.y *= s; a.z *= s; a.w *= s;
    *(float4*)&B[IX(i, j0)] = a;
    wsync();
    float *S, *Z;
    ns_sqrtm_w(B, B + MSZ, B + 2 * MSZ, B + 3 * MSZ, B + 4 * MSZ, B + 5 * MSZ, l, &S, &Z);
    cpy_w(S, Gs, l);
    cpy_w(Z, Gi, l);
  } else if (w == 1) {
    float* B = wb[1];
    g2l_w(rm, B, l);
    float *S, *Z;
    ns_sqrtm_w(B, B + MSZ, B + 2 * MSZ, B + 3 * MSZ, B + 4 * MSZ, B + 5 * MSZ, l, &S, &Z);
    cpy_w(S, Rs, l);
    cpy_w(Z, Ri, l);
  }
  __syncthreads();

  // --- stage C: 4 waves x 8 logmaps, accumulate L per wave ---
  {
    float* c0 = wb[w];               // Xb
    float* c1 = wb[w] + MSZ;         // T / L
    float* c2 = wb[w] + 2 * MSZ;     // S
    float* c3 = wb[w] + 3 * MSZ;     // R0
    float* c4 = wb[w] + 4 * MSZ;     // R1
    float* c5 = wb[w] + 5 * MSZ;     // Lacc
    setI_w(c5, 0.f, l);
    for (int r = 0; r < 8; ++r) {
      int b = w * 8 + r;
      g2l_w(ws + XM_O + b * 256, c0, l);
      mm_w(Gi, c0, c1, l);
      mm_w(c1, Gi, c2, l);
      sym_w(c2, l);
      logm_w(c2, c1, c3, c4, l);     // L in c1
      add_w(c5, c1, l);
    }
  }
  __syncthreads();

  // --- stage D: wave0 only ---
  if (w == 0) {
    float* b0 = wb[0];
    float* b1 = wb[0] + MSZ;
    float* b2 = wb[0] + 2 * MSZ;
    float* b3 = wb[0] + 3 * MSZ;
    float* b4 = wb[0] + 4 * MSZ;
    float* b5 = wb[0] + 5 * MSZ;
    // Lbar = sum of 4 accumulators / 32  -> b0
    {
      int i = l >> 2, j0 = (l & 3) << 2;
      float4 a = make_float4(0.f, 0.f, 0.f, 0.f);
      #pragma unroll
      for (int q = 0; q < 4; ++q) {
        float4 v = *(const float4*)&wb[q][5 * MSZ + IX(i, j0)];
        a.x += v.x; a.y += v.y; a.z += v.z; a.w += v.w;
      }
      float s = 1.f / NS;
      a.x *= s; a.y *= s; a.z *= s; a.w *= s;
      wsync();
      *(float4*)&b0[IX(i, j0)] = a;
      wsync();
    }
    float* E = expm_w(b0, b1, b2, l);       // exp(Lbar) (in b1)
    mm_w(Gs, E, b3, l);
    mm_w(b3, Gs, b4, l);                    // b4 = mean
    sym_w(b4, l);
    float *S, *Z;
    ns_sqrtm_w(b4, b0, b1, b2, b3, b5, l, &S, &Z);
    l2g_w(Z, ws + WI_O, l);                 // W = invsqrt(mean)
    // geodesic(running_mean, mean, 0.1) -> out tail
    mm_w(Ri, b4, b0, l);
    mm_w(b0, Ri, b1, l);                    // b1 = Ri*mean*Ri
    sym_w(b1, l);
    float c = trace16_w(b1) * (1.f / 16.f);
    mad_diag_w(b1, 1.f / c, 0.f, l);        // ~ I + E
    logm_w(b1, b0, b2, b3, l);              // b0 = log
    mad_diag_w(b0, 0.1f, 0.f, l);
    float* E2 = expm_w(b0, b1, b2, l);      // (in b1)
    mad_diag_w(E2, expf(0.1f * logf(c)), 0.f, l);
    mm_w(Rs, E2, b3, l);
    mm_w(b3, Rs, b0, l);
    l2g_w(b0, out + (size_t)NMAT * 256, l);
  }
}

// Bulk centering: Y = W*X*W. 6400 blocks x 256 thr; 16 matrices/block, 4/wave.
// Per-wave slabs, zero barriers. Global I/O: lane-contiguous float4 (1KB/wave/instr).
// LDS reads are 4-address broadcasts; W row + U row hoisted to VGPRs via b128.
__global__ __launch_bounds__(256) void k_center(const float* __restrict__ X,
                                                const float* __restrict__ ws,
                                                float* __restrict__ out) {
  __shared__ __align__(16) float Wl[MSZ];
  __shared__ __align__(16) float sX[4][SLAB];
  __shared__ __align__(16) float sU[4][SLAB];
  int t = threadIdx.x, w = t >> 6, l = t & 63;
  int i = l >> 2, j0 = (l & 3) << 2;

  // stage W (every wave writes the same values — benign race, no barrier)
  *(float4*)&Wl[IX(l >> 2, (l & 3) << 2)] = ((const float4*)(ws + WI_O))[l];
  wsync();

  // hoist W row i (W symmetric: row == column)
  float wr[16];
  #pragma unroll
  for (int c = 0; c < 4; ++c) {
    float4 v = *(const float4*)&Wl[IX(i, 4 * c)];
    wr[4 * c] = v.x; wr[4 * c + 1] = v.y; wr[4 * c + 2] = v.z; wr[4 * c + 3] = v.w;
  }

  long base = (long)blockIdx.x * 16 + w * 4;
  const float4* X4 = (const float4*)X;
  float4* O4 = (float4*)out;

  float4 xv = X4[base * 64 + l];
  #pragma unroll
  for (int it = 0; it < 4; ++it) {
    float4 xn = make_float4(0.f, 0.f, 0.f, 0.f);
    if (it < 3) xn = X4[(base + it + 1) * 64 + l];   // prefetch next matrix
    *(float4*)&sX[w][IX(i, j0)] = xv;
    wsync();
    // phase 1: U = W * X   (U[i][j0..3] = sum_k W[i][k] * X[k][j0..3])
    float4 u = make_float4(0.f, 0.f, 0.f, 0.f);
    #pragma unroll
    for (int k = 0; k < 16; ++k) {
      float4 b = *(const float4*)&sX[w][IX(k, j0)];
      float a = wr[k];
      u.x += a * b.x; u.y += a * b.y; u.z += a * b.z; u.w += a * b.w;
    }
    *(float4*)&sU[w][IX(i, j0)] = u;
    wsync();
    // hoist U row i
    float ur[16];
    #pragma unroll
    for (int c = 0; c < 4; ++c) {
      float4 v = *(const float4*)&sU[w][IX(i, 4 * c)];
      ur[4 * c] = v.x; ur[4 * c + 1] = v.y; ur[4 * c + 2] = v.z; ur[4 * c + 3] = v.w;
    }
    // phase 2: Y = U * W   (Y[i][j0..3] = sum_k U[i][k] * W[k][j0..3])
    float4 y = make_float4(0.f, 0.f, 0.f, 0.f);
    #pragma unroll
    for (int k = 0; k < 16; ++k) {
      float4 b = *(const float4*)&Wl[IX(k, j0)];
      float a = ur[k];
      y.x += a * b.x; y.y += a * b.y; y.z += a * b.z; y.w += a * b.w;
    }
    O4[(base + it) * 64 + l] = y;
    xv = xn;
  }
}

extern "C" void kernel_launch(void* const* d_in, const int* in_sizes, int n_in,
                              void* d_out, int out_size, void* d_ws, size_t ws_size,
                              hipStream_t stream) {
  (void)in_sizes; (void)n_in; (void)out_size; (void)ws_size;
  const float* X  = (const float*)d_in[0];
  const float* rm = (const float*)d_in[1];
  float* out = (float*)d_out;
  float* ws  = (float*)d_ws;

  k_part     <<<dim3(512),  dim3(256), 0, stream>>>(X, ws);
  k_spectral <<<dim3(1),    dim3(256), 0, stream>>>(rm, ws, out);
  k_center   <<<dim3(6400), dim3(256), 0, stream>>>(X, ws, out);
}